// Round 1
// baseline (15.764 us; speedup 1.0000x reference)
//
#include <hip/hip_runtime.h>

// Retina multi-scale glimpse:
//   x: (128, 3, 224, 224) f32, l: (128, 2) f32 in [-1,1]
//   out: (128, 9, 32, 32) f32
//   r0,c0 = int(224*(l+1)/2); patch = edge-padded(x)[r0:r0+128, c0:c0+128] (pad=64)
//   ch 0-2: maxpool4(patch), ch 3-5: maxpool2(patch[32:96,32:96]), ch 6-8: patch[48:80,48:80]

#define IMG 224

__global__ __launch_bounds__(256) void retina_kernel(
    const float* __restrict__ x, const float* __restrict__ l,
    float* __restrict__ out)
{
    const int total = 128 * 9 * 32 * 32;
    int idx = blockIdx.x * 256 + threadIdx.x;
    if (idx >= total) return;

    int xx = idx & 31;
    int yy = (idx >> 5) & 31;
    int ch = (idx >> 10) % 9;
    int b  = idx / (9 * 32 * 32);
    int scale = ch / 3;   // block-uniform (1024 outputs per (b,ch), 256-thread blocks)
    int c     = ch % 3;

    // Match JAX op order exactly: (224 * (l + 1.0)) / 2.0, truncate to int.
    float l0 = l[b * 2 + 0];
    float l1 = l[b * 2 + 1];
    int r0 = (int)(224.0f * (l0 + 1.0f) / 2.0f);
    int c0 = (int)(224.0f * (l1 + 1.0f) / 2.0f);
    // dynamic_slice clamps start to [0, 352-128]; l in [-1,1] keeps it in range,
    // but clamp for safety.
    r0 = min(max(r0, 0), 224);
    c0 = min(max(c0, 0), 224);

    const float* xb = x + ((size_t)(b * 3 + c)) * (IMG * IMG);

    int k, py0, px0;
    if (scale == 0)      { k = 4; py0 = 4 * yy;      px0 = 4 * xx;      }
    else if (scale == 1) { k = 2; py0 = 32 + 2 * yy; px0 = 32 + 2 * xx; }
    else                 { k = 1; py0 = 48 + yy;     px0 = 48 + xx;     }

    float m = -INFINITY;
    #pragma unroll 4
    for (int dy = 0; dy < k; ++dy) {
        int sr = r0 + py0 + dy - 64;          // padded -> source row
        sr = min(max(sr, 0), IMG - 1);        // edge padding = clamp
        const float* row = xb + sr * IMG;
        #pragma unroll 4
        for (int dx = 0; dx < k; ++dx) {
            int sc = c0 + px0 + dx - 64;
            sc = min(max(sc, 0), IMG - 1);
            m = fmaxf(m, row[sc]);
        }
    }
    out[idx] = m;
}

extern "C" void kernel_launch(void* const* d_in, const int* in_sizes, int n_in,
                              void* d_out, int out_size, void* d_ws, size_t ws_size,
                              hipStream_t stream) {
    const float* x = (const float*)d_in[0];
    const float* l = (const float*)d_in[1];
    float* out = (float*)d_out;

    const int total = 128 * 9 * 32 * 32;   // 1,179,648
    int blocks = (total + 255) / 256;      // 4608
    retina_kernel<<<blocks, 256, 0, stream>>>(x, l, out);
}

// Round 2
// 12.552 us; speedup vs baseline: 1.2559x; 1.2559x over previous
//
#include <hip/hip_runtime.h>

// Retina multi-scale glimpse, fused single-pass:
//   x: (128, 3, 224, 224) f32, l: (128, 2) f32 in [-1,1]
//   out: (128, 9, 32, 32) f32
//   r0,c0 = int(224*(l+1)/2); patch = edge-padded(x)[r0:r0+128, c0:c0+128] (pad=64)
//   ch 0-2: maxpool4(patch), ch 3-5: maxpool2(patch[32:96,32:96]), ch 6-8: patch[48:80,48:80]
//
// One thread owns one 4x4 patch tile (ty,tx in [0,32)): loads 16 values once,
// emits 1 scale-0 output; if the tile is inside the central 64x64 it also
// emits the 4 scale-1 outputs contained in it; if inside the central 32x32,
// the 16 scale-2 outputs. Every patch element is loaded exactly once.

#define IMG 224

__global__ __launch_bounds__(256) void retina_fused(
    const float* __restrict__ x, const float* __restrict__ l,
    float* __restrict__ out)
{
    int idx = blockIdx.x * 256 + threadIdx.x;   // grid sized exactly: no tail
    int tx = idx & 31;
    int ty = (idx >> 5) & 31;
    int c  = (idx >> 10) % 3;
    int b  = idx / (3 * 32 * 32);

    // Match JAX op order exactly: (224 * (l + 1.0)) / 2.0, truncate to int.
    float l0 = l[b * 2 + 0];
    float l1 = l[b * 2 + 1];
    int r0 = (int)(224.0f * (l0 + 1.0f) / 2.0f);
    int c0 = (int)(224.0f * (l1 + 1.0f) / 2.0f);
    r0 = min(max(r0, 0), 224);
    c0 = min(max(c0, 0), 224);

    const float* __restrict__ xb = x + (size_t)(b * 3 + c) * (IMG * IMG);

    // Clamped row offsets (edge padding = clamp) and col offsets, shared by
    // the whole 4x4 tile: 8 clamps for 16 loads.
    int rowoff[4], coloff[4];
    #pragma unroll
    for (int d = 0; d < 4; ++d) {
        int sr = r0 + 4 * ty + d - 64;
        rowoff[d] = min(max(sr, 0), IMG - 1) * IMG;
        int sc = c0 + 4 * tx + d - 64;
        coloff[d] = min(max(sc, 0), IMG - 1);
    }

    float v[4][4];
    #pragma unroll
    for (int dy = 0; dy < 4; ++dy)
        #pragma unroll
        for (int dx = 0; dx < 4; ++dx)
            v[dy][dx] = xb[rowoff[dy] + coloff[dx]];

    // scale 0: 4x4 max
    float m01   = fmaxf(fmaxf(v[0][0], v[0][1]), fmaxf(v[0][2], v[0][3]));
    float m11   = fmaxf(fmaxf(v[1][0], v[1][1]), fmaxf(v[1][2], v[1][3]));
    float m21   = fmaxf(fmaxf(v[2][0], v[2][1]), fmaxf(v[2][2], v[2][3]));
    float m31   = fmaxf(fmaxf(v[3][0], v[3][1]), fmaxf(v[3][2], v[3][3]));
    float m0 = fmaxf(fmaxf(m01, m11), fmaxf(m21, m31));

    float* __restrict__ ob = out + (size_t)(b * 9) * 1024;
    ob[(c << 10) + (ty << 5) + tx] = m0;

    // scale 1: tile inside central 64x64 (patch rows/cols [32,96)) <=> ty,tx in [8,24)
    if (ty >= 8 && ty < 24 && tx >= 8 && tx < 24) {
        float* __restrict__ o1 = ob + ((3 + c) << 10);
        int oy = 2 * (ty - 8);
        int ox = 2 * (tx - 8);
        #pragma unroll
        for (int sy = 0; sy < 2; ++sy)
            #pragma unroll
            for (int sx = 0; sx < 2; ++sx) {
                float q = fmaxf(fmaxf(v[2*sy][2*sx],   v[2*sy][2*sx+1]),
                                fmaxf(v[2*sy+1][2*sx], v[2*sy+1][2*sx+1]));
                o1[((oy + sy) << 5) + (ox + sx)] = q;
            }
    }

    // scale 2: tile inside central 32x32 (patch rows/cols [48,80)) <=> ty,tx in [12,20)
    if (ty >= 12 && ty < 20 && tx >= 12 && tx < 20) {
        float* __restrict__ o2 = ob + ((6 + c) << 10);
        int oy = 4 * (ty - 12);
        int ox = 4 * (tx - 12);
        #pragma unroll
        for (int dy = 0; dy < 4; ++dy)
            #pragma unroll
            for (int dx = 0; dx < 4; ++dx)
                o2[((oy + dy) << 5) + (ox + dx)] = v[dy][dx];
    }
}

extern "C" void kernel_launch(void* const* d_in, const int* in_sizes, int n_in,
                              void* d_out, int out_size, void* d_ws, size_t ws_size,
                              hipStream_t stream) {
    const float* x = (const float*)d_in[0];
    const float* l = (const float*)d_in[1];
    float* out = (float*)d_out;

    const int total_tiles = 128 * 3 * 32 * 32;   // 393,216 threads
    int blocks = total_tiles / 256;              // 1536, exact
    retina_fused<<<blocks, 256, 0, stream>>>(x, l, out);
}